// Round 8
// baseline (2151.558 us; speedup 1.0000x reference)
//
#include <hip/hip_runtime.h>

#define ZN 131072          // B*H*W rows
#define DD 64              // embedding dim
#define KK 1024            // codebook entries
#define BSTRIDE 262144     // 64*64*64 (per-batch stride in z)
#define DSTRIDE 4096       // per-d stride in z (H*W)
#define ZQ_ELEMS 8388608   // 32*64*64*64

// ---- workspace layout ----
// [0,8)                double   loss accumulator
// [8,12)               unsigned flagged-row count
// [16,4112)            float    csq32[1024]    (numpy-emulated fp32)
// [4112,528400)        float    zsq32[131072]  (numpy-emulated fp32)
// [528400,1052688)     int      worklist[131072] (n | prefilter_best<<17)
// [1052688,1314832)    float    cbT[64][1024]  (transposed codebook)
#define WS_CSQ_OFF   16
#define WS_ZSQ_OFF   4112
#define WS_WORK_OFF  528400
#define WS_CBT_OFF   1052688

typedef float v2f __attribute__((ext_vector_type(2)));

// numpy-emulated fp32 sum of a[i]^2, 64 elems (pairwise, 8 accumulators), from float*
__device__ __forceinline__ float np_sumsq64(const float* a) {
    float r0 = __fmul_rn(a[0], a[0]), r1 = __fmul_rn(a[1], a[1]);
    float r2 = __fmul_rn(a[2], a[2]), r3 = __fmul_rn(a[3], a[3]);
    float r4 = __fmul_rn(a[4], a[4]), r5 = __fmul_rn(a[5], a[5]);
    float r6 = __fmul_rn(a[6], a[6]), r7 = __fmul_rn(a[7], a[7]);
#pragma unroll
    for (int i = 8; i < 64; i += 8) {
        r0 = __fadd_rn(r0, __fmul_rn(a[i + 0], a[i + 0]));
        r1 = __fadd_rn(r1, __fmul_rn(a[i + 1], a[i + 1]));
        r2 = __fadd_rn(r2, __fmul_rn(a[i + 2], a[i + 2]));
        r3 = __fadd_rn(r3, __fmul_rn(a[i + 3], a[i + 3]));
        r4 = __fadd_rn(r4, __fmul_rn(a[i + 4], a[i + 4]));
        r5 = __fadd_rn(r5, __fmul_rn(a[i + 5], a[i + 5]));
        r6 = __fadd_rn(r6, __fmul_rn(a[i + 6], a[i + 6]));
        r7 = __fadd_rn(r7, __fmul_rn(a[i + 7], a[i + 7]));
    }
    return __fadd_rn(__fadd_rn(__fadd_rn(r0, r1), __fadd_rn(r2, r3)),
                     __fadd_rn(__fadd_rn(r4, r5), __fadd_rn(r6, r7)));
}

// same, from v2f[32] register array (never forms a float* -> stays in VGPRs)
#define NP_SUMSQ_V2F(dst, a)                                                      \
    {                                                                             \
        float r[8];                                                               \
        _Pragma("unroll") for (int j = 0; j < 8; ++j) {                           \
            float v = ((j) & 1) ? a[(j) >> 1].y : a[(j) >> 1].x;                  \
            r[j] = __fmul_rn(v, v);                                               \
        }                                                                         \
        _Pragma("unroll") for (int i = 8; i < 64; i += 8)                         \
            _Pragma("unroll") for (int j = 0; j < 8; ++j) {                       \
            float v = ((i + j) & 1) ? a[(i + j) >> 1].y : a[(i + j) >> 1].x;      \
            r[j] = __fadd_rn(r[j], __fmul_rn(v, v));                              \
        }                                                                         \
        dst = __fadd_rn(__fadd_rn(__fadd_rn(r[0], r[1]), __fadd_rn(r[2], r[3])), \
                        __fadd_rn(__fadd_rn(r[4], r[5]), __fadd_rn(r[6], r[7]))); \
    }

// -------- prep: cbT[d][k] = cb[k][d]; csq32[k] --------
__global__ __launch_bounds__(256) void vq_prep(const float* __restrict__ cb,
                                               float* __restrict__ cbT,
                                               float* __restrict__ csq) {
    int i = blockIdx.x * 256 + threadIdx.x;  // 0..65535
    int d = i >> 10, k = i & 1023;
    cbT[i] = cb[k * DD + d];
    if (i < KK) csq[i] = np_sumsq64(cb + i * DD);
}

// -------- fp32 prefilter argmin + fused zq/loss epilogue --------
// block = 256 thr = 4 waves; each thread owns 2 rows (n0 = base+tl,
// n1 = base+64+tl), each wave scans its SGPR-pinned 256-code range.
// LDS merge (min2 = min(winner.min2, losers' min1)); epilogue splits the
// 64 d's across the 4 waves: writes zq + fp32 loss partial -> f64 atomic.
__global__ __attribute__((amdgpu_waves_per_eu(2))) __launch_bounds__(256)
void vq_argmin(const float* __restrict__ z,
               const float* __restrict__ cb,
               const float* __restrict__ csq,
               float* __restrict__ zsq32,
               float* __restrict__ idxf_out,
               float* __restrict__ zq_out,
               unsigned* __restrict__ count,
               int* __restrict__ worklist,
               double* __restrict__ acc) {
    int tl = threadIdx.x & 63;
    int wv = __builtin_amdgcn_readfirstlane(threadIdx.x >> 6);  // SGPR wave id
    int base = blockIdx.x * 128;
    int n0 = base + tl, n1 = base + 64 + tl;
    int b0 = n0 >> 12, p0 = n0 & 4095;
    int b1 = n1 >> 12, p1 = n1 & 4095;
    const float* zp0 = z + (size_t)b0 * BSTRIDE + p0;
    const float* zp1 = z + (size_t)b1 * BSTRIDE + p1;

    v2f zr0[32], zr1[32];
#pragma unroll
    for (int j = 0; j < 32; ++j) {  // coalesced across lanes
        zr0[j].x = zp0[(size_t)(2 * j + 0) * DSTRIDE];
        zr0[j].y = zp0[(size_t)(2 * j + 1) * DSTRIDE];
    }
#pragma unroll
    for (int j = 0; j < 32; ++j) {
        zr1[j].x = zp1[(size_t)(2 * j + 0) * DSTRIDE];
        zr1[j].y = zp1[(size_t)(2 * j + 1) * DSTRIDE];
    }

    if (wv == 0) {
        float zs0, zs1;
        NP_SUMSQ_V2F(zs0, zr0);
        NP_SUMSQ_V2F(zs1, zr1);
        zsq32[n0] = zs0;
        zsq32[n1] = zs1;
    }

    float amin1 = 3.4e38f, amin2 = 3.4e38f, bmin1 = 3.4e38f, bmin2 = 3.4e38f;
    int abest = 0, bbest = 0;
    int kbase = wv << 8;  // SGPR
#pragma unroll 2
    for (int kk = 0; kk < 256; ++kk) {
        int k = kbase + kk;  // uniform -> scalar loads
        const v2f* c = (const v2f*)(cb + k * DD);
        v2f a0 = {0.f, 0.f}, a1 = {0.f, 0.f}, a2 = {0.f, 0.f}, a3 = {0.f, 0.f};
        v2f e0 = {0.f, 0.f}, e1 = {0.f, 0.f}, e2 = {0.f, 0.f}, e3 = {0.f, 0.f};
#pragma unroll
        for (int j = 0; j < 32; j += 4) {
            v2f c0 = c[j + 0], c1 = c[j + 1], c2 = c[j + 2], c3 = c[j + 3];
            a0 = __builtin_elementwise_fma(zr0[j + 0], c0, a0);
            a1 = __builtin_elementwise_fma(zr0[j + 1], c1, a1);
            a2 = __builtin_elementwise_fma(zr0[j + 2], c2, a2);
            a3 = __builtin_elementwise_fma(zr0[j + 3], c3, a3);
            e0 = __builtin_elementwise_fma(zr1[j + 0], c0, e0);
            e1 = __builtin_elementwise_fma(zr1[j + 1], c1, e1);
            e2 = __builtin_elementwise_fma(zr1[j + 2], c2, e2);
            e3 = __builtin_elementwise_fma(zr1[j + 3], c3, e3);
        }
        float cs = csq[k];
        v2f sa = (a0 + a1) + (a2 + a3);
        v2f se = (e0 + e1) + (e2 + e3);
        float dist0 = fmaf(-2.f, sa.x + sa.y, cs);
        float dist1 = fmaf(-2.f, se.x + se.y, cs);
        bool lt0 = dist0 < amin1;  // strict: lowest k on ties
        float o0 = amin1;
        amin1 = lt0 ? dist0 : amin1;
        amin2 = lt0 ? o0 : fminf(amin2, dist0);
        abest = lt0 ? k : abest;
        bool lt1 = dist1 < bmin1;
        float o1 = bmin1;
        bmin1 = lt1 ? dist1 : bmin1;
        bmin2 = lt1 ? o1 : fminf(bmin2, dist1);
        bbest = lt1 ? k : bbest;
    }

    __shared__ float smin1[4][2][64];
    __shared__ float smin2[4][2][64];
    __shared__ int sbest[4][2][64];
    smin1[wv][0][tl] = amin1; smin2[wv][0][tl] = amin2; sbest[wv][0][tl] = abest;
    smin1[wv][1][tl] = bmin1; smin2[wv][1][tl] = bmin2; sbest[wv][1][tl] = bbest;
    __syncthreads();

    // all waves redo the merge (deterministic) so everyone knows the winners
    float g1[2], g2[2];
    int gb[2];
#pragma unroll
    for (int r = 0; r < 2; ++r) {
        g1[r] = smin1[0][r][tl]; g2[r] = smin2[0][r][tl]; gb[r] = sbest[0][r][tl];
#pragma unroll
        for (int c = 1; c < 4; ++c) {
            float c1 = smin1[c][r][tl];
            if (c1 < g1[r]) {                // strict: ties keep lower-k chunk
                g2[r] = fminf(g1[r], smin2[c][r][tl]);
                gb[r] = sbest[c][r][tl];
                g1[r] = c1;
            } else {
                g2[r] = fminf(g2[r], c1);
            }
        }
    }

    if (wv == 0) {
        idxf_out[n0] = (float)gb[0];
        idxf_out[n1] = (float)gb[1];
        // reference fp32 rounding noise can only flip ranking for gaps
        // < ~1.6e-5; flag with 12x margin -> exact emulation pass.
        if (g2[0] - g1[0] < 2e-4f) worklist[atomicAdd(count, 1u)] = n0 | (gb[0] << 17);
        if (g2[1] - g1[1] < 2e-4f) worklist[atomicAdd(count, 1u)] = n1 | (gb[1] << 17);
    }

    // epilogue: wave wv handles d in [wv*16, wv*16+16) for both rows.
    // z re-loaded from global (L1-hot, coalesced) to avoid dynamic VGPR indexing.
    float s = 0.f;
    float* qp0 = zq_out + (size_t)b0 * BSTRIDE + p0;
    float* qp1 = zq_out + (size_t)b1 * BSTRIDE + p1;
    const float* c0r = cb + gb[0] * DD;
    const float* c1r = cb + gb[1] * DD;
#pragma unroll
    for (int j = 0; j < 16; ++j) {
        int d = (wv << 4) + j;
        float q0 = c0r[d];
        float df0 = q0 - zp0[(size_t)d * DSTRIDE];
        s = fmaf(df0, df0, s);
        qp0[(size_t)d * DSTRIDE] = q0;
        float q1 = c1r[d];
        float df1 = q1 - zp1[(size_t)d * DSTRIDE];
        s = fmaf(df1, df1, s);
        qp1[(size_t)d * DSTRIDE] = q1;
    }
#pragma unroll
    for (int off = 32; off; off >>= 1) s += __shfl_down(s, off, 64);
    __shared__ float partial[4];
    if (tl == 0) partial[wv] = s;
    __syncthreads();
    if (threadIdx.x == 0) {
        float t = (partial[0] + partial[1]) + (partial[2] + partial[3]);
        atomicAdd(acc, (double)t);
    }
}

// -------- reference-fp32-emulated argmin for flagged rows: block per row ----
// z row staged in LDS once; thread t -> codes {t, t+256, t+512, t+768}
// (coalesced cbT); wave shuffle-reduce on packed u64, 4-way LDS merge.
// If winner != prefilter best: rewrite zq row + f64 loss delta.
__global__ __launch_bounds__(256) void vq_refine(const float* __restrict__ z,
                                                 const float* __restrict__ cbT,
                                                 const float* __restrict__ csq,
                                                 const float* __restrict__ zsq32,
                                                 const unsigned* __restrict__ count,
                                                 const int* __restrict__ worklist,
                                                 float* __restrict__ idxf_out,
                                                 float* __restrict__ zq_out,
                                                 double* __restrict__ acc) {
    __shared__ float zrow[DD];
    __shared__ unsigned long long wres[4];
    __shared__ int s_kn;
    unsigned cnt = *count;
    int t = threadIdx.x;
    int wv = t >> 6, tl = t & 63;
    for (unsigned r = blockIdx.x; r < cnt; r += gridDim.x) {
        __syncthreads();  // protect zrow/s_kn across iterations
        int e = worklist[r];
        int n = e & 131071;
        int kold = e >> 17;
        int b = n >> 12, p = n & 4095;
        if (t < DD) zrow[t] = z[(size_t)b * BSTRIDE + (size_t)t * DSTRIDE + p];
        __syncthreads();

        float zsq = zsq32[n];
        unsigned long long pk = ~0ull;
#pragma unroll
        for (int j = 0; j < 4; ++j) {
            int k = j * 256 + t;  // ascending within thread
            double a0 = 0.0, a1 = 0.0, a2 = 0.0, a3 = 0.0;
#pragma unroll
            for (int d = 0; d < DD; d += 4) {
                a0 = fma((double)zrow[d + 0], (double)cbT[(d + 0) * KK + k], a0);
                a1 = fma((double)zrow[d + 1], (double)cbT[(d + 1) * KK + k], a1);
                a2 = fma((double)zrow[d + 2], (double)cbT[(d + 2) * KK + k], a2);
                a3 = fma((double)zrow[d + 3], (double)cbT[(d + 3) * KK + k], a3);
            }
            double dot = (a0 + a1) + (a2 + a3);
            float twoC = (float)(2.0 * dot);  // ~sgemm output, correctly rounded
            float dist = __fsub_rn(__fadd_rn(zsq, csq[k]), twoC);  // ref fp32 ops
            unsigned ub = __float_as_uint(dist);
            ub = (ub & 0x80000000u) ? ~ub : (ub | 0x80000000u);  // order-preserving
            unsigned long long cand = ((unsigned long long)ub << 32) | (unsigned)k;
            pk = cand < pk ? cand : pk;  // u64 min: lowest dist, then lowest k
        }
#pragma unroll
        for (int off = 32; off; off >>= 1) {
            unsigned long long o = (unsigned long long)__shfl_xor((long long)pk, off, 64);
            pk = pk < o ? pk : o;
        }
        if (tl == 0) wres[wv] = pk;
        __syncthreads();
        if (t == 0) {
            unsigned long long m = wres[0];
            m = wres[1] < m ? wres[1] : m;
            m = wres[2] < m ? wres[2] : m;
            m = wres[3] < m ? wres[3] : m;
            int kn = (int)(unsigned)(m & 0xFFFFFFFFull);
            idxf_out[n] = (float)kn;
            s_kn = kn;
        }
        __syncthreads();
        int kn = s_kn;
        if (kn != kold && t < DD) {
            float zv = zrow[t];
            float cn = cbT[t * KK + kn];
            float co = cbT[t * KK + kold];
            zq_out[(size_t)b * BSTRIDE + (size_t)t * DSTRIDE + p] = cn;
            float dn = cn - zv, doo = co - zv;
            float dl = fmaf(dn, dn, -(doo * doo));
#pragma unroll
            for (int off = 32; off; off >>= 1) dl += __shfl_down(dl, off, 64);
            if (t == 0) atomicAdd(acc, (double)dl);
        }
    }
}

__global__ void vq_finalize(const double* __restrict__ acc, float* __restrict__ loss_out) {
    *loss_out = (float)(1.25 * (*acc) / (double)ZQ_ELEMS);
}

extern "C" void kernel_launch(void* const* d_in, const int* in_sizes, int n_in,
                              void* d_out, int out_size, void* d_ws, size_t ws_size,
                              hipStream_t stream) {
    const float* z = (const float*)d_in[0];
    const float* cb = (const float*)d_in[1];
    float* out = (float*)d_out;

    float* zq_out = out;                   // [0, 8388608)
    float* loss_out = out + ZQ_ELEMS;      // [8388608]
    float* idxf_out = out + ZQ_ELEMS + 1;  // [8388609, +131072)

    char* ws = (char*)d_ws;
    double* acc = (double*)ws;
    unsigned* count = (unsigned*)(ws + 8);
    float* csq = (float*)(ws + WS_CSQ_OFF);
    float* zsq32 = (float*)(ws + WS_ZSQ_OFF);
    int* worklist = (int*)(ws + WS_WORK_OFF);
    float* cbT = (float*)(ws + WS_CBT_OFF);

    hipMemsetAsync(d_ws, 0, 16, stream);  // acc=0, count=0

    vq_prep<<<KK * DD / 256, 256, 0, stream>>>(cb, cbT, csq);
    vq_argmin<<<ZN / 128, 256, 0, stream>>>(z, cb, csq, zsq32, idxf_out, zq_out,
                                            count, worklist, acc);
    vq_refine<<<4096, 256, 0, stream>>>(z, cbT, csq, zsq32, count, worklist,
                                        idxf_out, zq_out, acc);
    vq_finalize<<<1, 1, 0, stream>>>(acc, loss_out);
}

// Round 9
// 554.865 us; speedup vs baseline: 3.8776x; 3.8776x over previous
//
#include <hip/hip_runtime.h>

#define ZN 131072          // B*H*W rows
#define DD 64              // embedding dim
#define KK 1024            // codebook entries
#define BSTRIDE 262144     // 64*64*64 (per-batch stride in z)
#define DSTRIDE 4096       // per-d stride in z (H*W)
#define ZQ_ELEMS 8388608   // 32*64*64*64

// ---- workspace layout ----
// [0,8)                double   loss accumulator
// [8,12)               unsigned flagged-row count
// [16,4112)            float    csq32[1024]    (numpy-emulated fp32)
// [4112,528400)        float    zsq32[131072]  (numpy-emulated fp32)
// [528400,1052688)     int      worklist[131072]
// [1052688,1314832)    float    cbT[64][1024]  (transposed codebook)
#define WS_CSQ_OFF   16
#define WS_ZSQ_OFF   4112
#define WS_WORK_OFF  528400
#define WS_CBT_OFF   1052688

typedef float v2f __attribute__((ext_vector_type(2)));

// numpy-emulated fp32 sum of a[i]^2 over 64 elems (pairwise, 8 accumulators).
__device__ __forceinline__ float np_sumsq64(const float* a) {
    float r0 = __fmul_rn(a[0], a[0]), r1 = __fmul_rn(a[1], a[1]);
    float r2 = __fmul_rn(a[2], a[2]), r3 = __fmul_rn(a[3], a[3]);
    float r4 = __fmul_rn(a[4], a[4]), r5 = __fmul_rn(a[5], a[5]);
    float r6 = __fmul_rn(a[6], a[6]), r7 = __fmul_rn(a[7], a[7]);
#pragma unroll
    for (int i = 8; i < 64; i += 8) {
        r0 = __fadd_rn(r0, __fmul_rn(a[i + 0], a[i + 0]));
        r1 = __fadd_rn(r1, __fmul_rn(a[i + 1], a[i + 1]));
        r2 = __fadd_rn(r2, __fmul_rn(a[i + 2], a[i + 2]));
        r3 = __fadd_rn(r3, __fmul_rn(a[i + 3], a[i + 3]));
        r4 = __fadd_rn(r4, __fmul_rn(a[i + 4], a[i + 4]));
        r5 = __fadd_rn(r5, __fmul_rn(a[i + 5], a[i + 5]));
        r6 = __fadd_rn(r6, __fmul_rn(a[i + 6], a[i + 6]));
        r7 = __fadd_rn(r7, __fmul_rn(a[i + 7], a[i + 7]));
    }
    return __fadd_rn(__fadd_rn(__fadd_rn(r0, r1), __fadd_rn(r2, r3)),
                     __fadd_rn(__fadd_rn(r4, r5), __fadd_rn(r6, r7)));
}

// -------- prep: cbT[d][k] = cb[k][d]; csq32[k] --------
__global__ __launch_bounds__(256) void vq_prep(const float* __restrict__ cb,
                                               float* __restrict__ cbT,
                                               float* __restrict__ csq) {
    int i = blockIdx.x * 256 + threadIdx.x;  // 0..65535
    int d = i >> 10, k = i & 1023;
    cbT[i] = cb[k * DD + d];
    if (i < KK) csq[i] = np_sumsq64(cb + i * DD);
}

// -------- fp32 prefilter argmin (R7-proven: 262 us, 44 VGPR) --------
// block = 256 threads = 64 rows x 4 waves; wave w scans codes
// [w*256, w*256+256) — k-base pinned to an SGPR via readfirstlane so
// codebook/csq loads stay scalar (s_load broadcast). z row in 32 x float2
// VGPRs; waves_per_eu(2) = min only (no spill, no max cap). Grid = 2048
// blocks. LDS merge: global min2 = min(winner.min2, losers' min1).
__global__ __attribute__((amdgpu_waves_per_eu(2))) __launch_bounds__(256)
void vq_argmin(const float* __restrict__ z,
               const float* __restrict__ cb,
               const float* __restrict__ csq,
               float* __restrict__ zsq32,
               float* __restrict__ idxf_out,
               unsigned* __restrict__ count,
               int* __restrict__ worklist) {
    int tl = threadIdx.x & 63;
    int wv = __builtin_amdgcn_readfirstlane(threadIdx.x >> 6);  // SGPR wave id
    int n = blockIdx.x * 64 + tl;
    int b = n >> 12, p = n & 4095;
    const float* zp = z + (size_t)b * BSTRIDE + p;

    v2f zr[32];
#pragma unroll
    for (int j = 0; j < 32; ++j) {  // coalesced across lanes (stride-4096 per d)
        zr[j].x = zp[(size_t)(2 * j + 0) * DSTRIDE];
        zr[j].y = zp[(size_t)(2 * j + 1) * DSTRIDE];
    }

    if (wv == 0) {
        // numpy-emulated fp32 ||z||^2 (same pairwise-8 order as np.sum)
#define ZA(i) (((i) & 1) ? zr[(i) >> 1].y : zr[(i) >> 1].x)
        float r[8];
#pragma unroll
        for (int j = 0; j < 8; ++j) r[j] = __fmul_rn(ZA(j), ZA(j));
#pragma unroll
        for (int i = 8; i < 64; i += 8)
#pragma unroll
            for (int j = 0; j < 8; ++j)
                r[j] = __fadd_rn(r[j], __fmul_rn(ZA(i + j), ZA(i + j)));
        zsq32[n] = __fadd_rn(__fadd_rn(__fadd_rn(r[0], r[1]), __fadd_rn(r[2], r[3])),
                             __fadd_rn(__fadd_rn(r[4], r[5]), __fadd_rn(r[6], r[7])));
#undef ZA
    }

    float min1 = 3.4e38f, min2 = 3.4e38f;
    int best = 0;
    int kbase = wv << 8;  // SGPR
#pragma unroll 2
    for (int kk = 0; kk < 256; ++kk) {
        int k = kbase + kk;  // uniform -> scalar loads
        const v2f* c = (const v2f*)(cb + k * DD);
        v2f a0 = {0.f, 0.f}, a1 = {0.f, 0.f}, a2 = {0.f, 0.f}, a3 = {0.f, 0.f};
#pragma unroll
        for (int j = 0; j < 32; j += 4) {
            a0 = __builtin_elementwise_fma(zr[j + 0], c[j + 0], a0);
            a1 = __builtin_elementwise_fma(zr[j + 1], c[j + 1], a1);
            a2 = __builtin_elementwise_fma(zr[j + 2], c[j + 2], a2);
            a3 = __builtin_elementwise_fma(zr[j + 3], c[j + 3], a3);
        }
        v2f s = (a0 + a1) + (a2 + a3);
        float dot = s.x + s.y;
        float dist = fmaf(-2.f, dot, csq[k]);
        bool lt = dist < min1;  // strict: keeps lowest k on ties
        float old1 = min1;
        min1 = lt ? dist : min1;
        min2 = lt ? old1 : fminf(min2, dist);
        best = lt ? k : best;
    }

    __shared__ float smin1[4][64];
    __shared__ float smin2[4][64];
    __shared__ int sbest[4][64];
    smin1[wv][tl] = min1;
    smin2[wv][tl] = min2;
    sbest[wv][tl] = best;
    __syncthreads();

    if (wv == 0) {
        float g1 = smin1[0][tl], g2 = smin2[0][tl];
        int gb = sbest[0][tl];
#pragma unroll
        for (int c = 1; c < 4; ++c) {
            float c1 = smin1[c][tl];
            if (c1 < g1) {                 // strict: ties keep lower-k chunk
                g2 = fminf(g1, smin2[c][tl]);
                gb = sbest[c][tl];
                g1 = c1;
            } else {
                g2 = fminf(g2, c1);
            }
        }
        idxf_out[n] = (float)gb;
        // reference fp32 rounding noise can only flip ranking for gaps
        // < ~1.6e-5; flag with 12x margin -> exact emulation pass.
        if (g2 - g1 < 2e-4f) worklist[atomicAdd(count, 1u)] = n;
    }
}

// -------- reference-fp32-emulated argmin for flagged rows: WAVE per row ----
// z row staged in this wave's LDS slice (broadcast reads). Thread tl covers
// codes k = 64*j + tl, j=0..15 -> 16 persistent f64 accumulators (32 VGPR),
// d-outer loop (#pragma unroll 2 bounds live range — R8's spill lesson).
// cbT loads lane-coalesced; in-wave u64 shuffle-min; lane 0 writes idxf.
__global__ __launch_bounds__(256) void vq_refine(const float* __restrict__ z,
                                                 const float* __restrict__ cbT,
                                                 const float* __restrict__ csq,
                                                 const float* __restrict__ zsq32,
                                                 const unsigned* __restrict__ count,
                                                 const int* __restrict__ worklist,
                                                 float* __restrict__ idxf_out) {
    __shared__ float zrow[4][DD];
    unsigned cnt = *count;
    int tl = threadIdx.x & 63;
    int wv = threadIdx.x >> 6;
    unsigned wave = blockIdx.x * 4 + wv;
    unsigned nwaves = gridDim.x * 4;
    for (unsigned r = wave; r < cnt; r += nwaves) {
        int n = worklist[r];
        int b = n >> 12, p = n & 4095;
        zrow[wv][tl] = z[(size_t)b * BSTRIDE + (size_t)tl * DSTRIDE + p];
        // same-wave LDS dep: compiler inserts lgkmcnt wait; no block sync needed

        double acc[16];
#pragma unroll
        for (int j = 0; j < 16; ++j) acc[j] = 0.0;
#pragma unroll 2
        for (int d = 0; d < DD; ++d) {
            double zd = (double)zrow[wv][d];  // LDS broadcast
            const float* crow = cbT + d * KK + tl;
#pragma unroll
            for (int j = 0; j < 16; ++j)  // lane-coalesced 256B loads
                acc[j] = fma(zd, (double)crow[64 * j], acc[j]);
        }

        float zsq = zsq32[n];  // wave-uniform
        unsigned long long pk = ~0ull;
#pragma unroll
        for (int j = 0; j < 16; ++j) {
            int k = 64 * j + tl;
            float twoC = (float)(2.0 * acc[j]);  // ~sgemm output, corr. rounded
            float dist = __fsub_rn(__fadd_rn(zsq, csq[k]), twoC);  // ref fp32 ops
            unsigned ub = __float_as_uint(dist);
            ub = (ub & 0x80000000u) ? ~ub : (ub | 0x80000000u);  // order-preserving
            unsigned long long cand = ((unsigned long long)ub << 32) | (unsigned)k;
            pk = cand < pk ? cand : pk;  // min dist, then lowest k
        }
#pragma unroll
        for (int off = 32; off; off >>= 1) {
            unsigned long long o = (unsigned long long)__shfl_xor((long long)pk, off, 64);
            pk = pk < o ? pk : o;
        }
        if (tl == 0) idxf_out[n] = (float)(unsigned)(pk & 0xFFFFFFFFull);
    }
}

// -------- gather z_q + fused loss partial reduction (R7-proven) --------
__global__ __launch_bounds__(256) void vq_gather_loss(const float* __restrict__ z,
                                                      const float* __restrict__ cb,
                                                      const float* __restrict__ idxf,
                                                      float* __restrict__ zq_out,
                                                      double* __restrict__ acc) {
    int n = blockIdx.x * 256 + threadIdx.x;
    int b = n >> 12, p = n & 4095;
    const float* zp = z + (size_t)b * BSTRIDE + p;
    float* qp = zq_out + (size_t)b * BSTRIDE + p;
    int k = (int)idxf[n];
    const float* c = cb + k * DD;

    float s = 0.f;
#pragma unroll
    for (int d = 0; d < DD; ++d) {
        float q = c[d];
        float diff = q - zp[(size_t)d * DSTRIDE];
        s = fmaf(diff, diff, s);
        qp[(size_t)d * DSTRIDE] = q;  // z_q_st == z_q numerically
    }

#pragma unroll
    for (int off = 32; off; off >>= 1) s += __shfl_down(s, off, 64);
    __shared__ float partial[4];
    if ((threadIdx.x & 63) == 0) partial[threadIdx.x >> 6] = s;
    __syncthreads();
    if (threadIdx.x == 0) {
        float t = (partial[0] + partial[1]) + (partial[2] + partial[3]);
        atomicAdd(acc, (double)t);
    }
}

__global__ void vq_finalize(const double* __restrict__ acc, float* __restrict__ loss_out) {
    *loss_out = (float)(1.25 * (*acc) / (double)ZQ_ELEMS);
}

extern "C" void kernel_launch(void* const* d_in, const int* in_sizes, int n_in,
                              void* d_out, int out_size, void* d_ws, size_t ws_size,
                              hipStream_t stream) {
    const float* z = (const float*)d_in[0];
    const float* cb = (const float*)d_in[1];
    float* out = (float*)d_out;

    float* zq_out = out;                   // [0, 8388608)
    float* loss_out = out + ZQ_ELEMS;      // [8388608]
    float* idxf_out = out + ZQ_ELEMS + 1;  // [8388609, +131072)

    char* ws = (char*)d_ws;
    double* acc = (double*)ws;
    unsigned* count = (unsigned*)(ws + 8);
    float* csq = (float*)(ws + WS_CSQ_OFF);
    float* zsq32 = (float*)(ws + WS_ZSQ_OFF);
    int* worklist = (int*)(ws + WS_WORK_OFF);
    float* cbT = (float*)(ws + WS_CBT_OFF);

    hipMemsetAsync(d_ws, 0, 16, stream);  // acc=0, count=0

    vq_prep<<<KK * DD / 256, 256, 0, stream>>>(cb, cbT, csq);
    vq_argmin<<<ZN / 64, 256, 0, stream>>>(z, cb, csq, zsq32, idxf_out, count, worklist);
    vq_refine<<<1024, 256, 0, stream>>>(z, cbT, csq, zsq32, count, worklist, idxf_out);
    vq_gather_loss<<<ZN / 256, 256, 0, stream>>>(z, cb, idxf_out, zq_out, acc);
    vq_finalize<<<1, 1, 0, stream>>>(acc, loss_out);
}